// Round 11
// baseline (179.842 us; speedup 1.0000x reference)
//
#include <hip/hip_runtime.h>
#include <hip/hip_bf16.h>
#include <stdint.h>

#define NN 8192
#define FD 256
#define SLOPE 0.2f
#define LOG2E 1.44269504088896f

typedef float f32x4_t __attribute__((ext_vector_type(4)));
typedef __bf16 bf16x8_t __attribute__((ext_vector_type(8)));
typedef unsigned short u16x8_t __attribute__((ext_vector_type(8)));

__device__ __forceinline__ unsigned short f2bf(float x) {
  unsigned int u = __builtin_bit_cast(unsigned int, x);
  u += 0x7FFFu + ((u >> 16) & 1u);  // RNE
  return (unsigned short)(u >> 16);
}

__device__ __forceinline__ void gload_lds16(const void* g, void* l) {
  __builtin_amdgcn_global_load_lds(
      (const __attribute__((address_space(1))) uint32_t*)g,
      (__attribute__((address_space(3))) uint32_t*)l, 16, 0, 0);
}

// ---------------- kernel 0: c1/c2[k] = sum_f W[f][k]*a{1,2}[f] ----------------
__global__ void gat_cvec(const float* __restrict__ W, const float* __restrict__ a,
                         float* __restrict__ c1, float* __restrict__ c2) {
  const int k = threadIdx.x;
  float acc1 = 0.f, acc2 = 0.f;
#pragma unroll 8
  for (int f = 0; f < FD; ++f) {
    float w = W[f * FD + k];
    acc1 = fmaf(w, a[f], acc1);
    acc2 = fmaf(w, a[FD + f], acc2);
  }
  c1[k] = acc1;
  c2[k] = acc2;
}

// ---- fused prep: blocks [0,512) wht | [512,2560) pack | [2560,4608) svec ----
__launch_bounds__(256)
__global__ void gat_prep(const float* __restrict__ h, const float* __restrict__ W,
                         const int* __restrict__ adj, const float* __restrict__ c1,
                         const float* __restrict__ c2,
                         unsigned short* __restrict__ whT2,
                         unsigned long long* __restrict__ mask64,
                         float* __restrict__ s1, float* __restrict__ s2) {
  __shared__ __align__(16) float hT[64][64];
  __shared__ __align__(16) float wT[64][64];
  const int b = blockIdx.x;
  const int t = threadIdx.x;

  if (b < 512) {
    // wht: Wh = h @ W^T, tiled store whT2[i/32][(i%32)/8][f][i%8]
    const int i0 = (b & 127) * 64;
    const int f0 = (b >> 7) * 64;
    const int r = t & 63;
    const int kq = t >> 6;
    const int ty = t >> 4;
    const int tx = t & 15;
    float acc[4][4] = {};
    for (int k0 = 0; k0 < FD; k0 += 64) {
#pragma unroll
      for (int kk = 0; kk < 16; kk += 4) {
        float4 v = *(const float4*)(h + (size_t)(i0 + r) * FD + k0 + kq * 16 + kk);
        hT[kq * 16 + kk + 0][r] = v.x;
        hT[kq * 16 + kk + 1][r] = v.y;
        hT[kq * 16 + kk + 2][r] = v.z;
        hT[kq * 16 + kk + 3][r] = v.w;
        float4 u = *(const float4*)(W + (size_t)(f0 + r) * FD + k0 + kq * 16 + kk);
        wT[kq * 16 + kk + 0][r] = u.x;
        wT[kq * 16 + kk + 1][r] = u.y;
        wT[kq * 16 + kk + 2][r] = u.z;
        wT[kq * 16 + kk + 3][r] = u.w;
      }
      __syncthreads();
#pragma unroll 8
      for (int kk = 0; kk < 64; ++kk) {
        float4 av = *(const float4*)&hT[kk][ty * 4];
        float4 bv = *(const float4*)&wT[kk][tx * 4];
        acc[0][0] = fmaf(av.x, bv.x, acc[0][0]);
        acc[0][1] = fmaf(av.x, bv.y, acc[0][1]);
        acc[0][2] = fmaf(av.x, bv.z, acc[0][2]);
        acc[0][3] = fmaf(av.x, bv.w, acc[0][3]);
        acc[1][0] = fmaf(av.y, bv.x, acc[1][0]);
        acc[1][1] = fmaf(av.y, bv.y, acc[1][1]);
        acc[1][2] = fmaf(av.y, bv.z, acc[1][2]);
        acc[1][3] = fmaf(av.y, bv.w, acc[1][3]);
        acc[2][0] = fmaf(av.z, bv.x, acc[2][0]);
        acc[2][1] = fmaf(av.z, bv.y, acc[2][1]);
        acc[2][2] = fmaf(av.z, bv.z, acc[2][2]);
        acc[2][3] = fmaf(av.z, bv.w, acc[2][3]);
        acc[3][0] = fmaf(av.w, bv.x, acc[3][0]);
        acc[3][1] = fmaf(av.w, bv.y, acc[3][1]);
        acc[3][2] = fmaf(av.w, bv.z, acc[3][2]);
        acc[3][3] = fmaf(av.w, bv.w, acc[3][3]);
      }
      __syncthreads();
    }
    const int iv = i0 + ty * 4;  // 4 consecutive i, same 8-group
#pragma unroll
    for (int j = 0; j < 4; ++j) {
      const int f = f0 + tx * 4 + j;
      ushort4 o;
      o.x = f2bf(acc[0][j]);
      o.y = f2bf(acc[1][j]);
      o.z = f2bf(acc[2][j]);
      o.w = f2bf(acc[3][j]);
      *(ushort4*)(whT2 + (size_t)(iv >> 5) * 8192 + ((iv >> 3) & 3) * 2048 +
                  (size_t)f * 8 + (iv & 7)) = o;
    }
  } else if (b < 2560) {
    // pack: adj -> 64-bit ballot mask, coalesced
    const int vb = b - 512;
    const int lane = t & 63;
    const int w = t >> 6;
    const size_t ngroups = (size_t)NN * NN / 256;
    const size_t nw = (size_t)2048 * 4;
    for (size_t g = (size_t)vb * 4 + w; g < ngroups; g += nw) {
      const int* p = adj + g * 256 + lane;
      int v0 = p[0];
      int v1 = p[64];
      int v2 = p[128];
      int v3 = p[192];
      unsigned long long m0 = __ballot(v0 != 0);
      unsigned long long m1 = __ballot(v1 != 0);
      unsigned long long m2 = __ballot(v2 != 0);
      unsigned long long m3 = __ballot(v3 != 0);
      if (lane < 4) {
        unsigned long long mv = lane == 0 ? m0 : lane == 1 ? m1 : lane == 2 ? m2 : m3;
        mask64[g * 4 + lane] = mv;
      }
    }
  } else {
    // svec: s1/s2[i] = (h[i].c)*log2e
    const int i = (b - 2560) * 4 + (t >> 6);
    const int lane = t & 63;
    float4 hv = *(const float4*)(h + (size_t)i * FD + lane * 4);
    float4 u = *(const float4*)(c1 + lane * 4);
    float4 v = *(const float4*)(c2 + lane * 4);
    float d1 = hv.x * u.x + hv.y * u.y + hv.z * u.z + hv.w * u.w;
    float d2 = hv.x * v.x + hv.y * v.y + hv.z * v.z + hv.w * v.w;
#pragma unroll
    for (int m = 1; m < 64; m <<= 1) {
      d1 += __shfl_xor(d1, m, 64);
      d2 += __shfl_xor(d2, m, 64);
    }
    if (lane == 0) {
      s1[i] = d1 * LOG2E;
      s2[i] = d2 * LOG2E;
    }
  }
}

// ---- one MFMA A-fragment of P (8 cols) from an 8-bit mask; exp2 domain ------
__device__ __forceinline__ bf16x8_t make_afrag(float s1r, const float4& slo,
                                               const float4& shi, unsigned int mbyte,
                                               float& lsum) {
  const float sv[8] = {slo.x, slo.y, slo.z, slo.w, shi.x, shi.y, shi.z, shi.w};
  u16x8_t ru;
#pragma unroll
  for (int c = 0; c < 8; ++c) {
    float x = s1r + sv[c];
    x = fmaxf(x, SLOPE * x);
    float pv = exp2f(x);
    pv = ((mbyte >> c) & 1u) ? pv : 0.f;
    lsum += pv;
    ru[c] = f2bf(pv);
  }
  return __builtin_bit_cast(bf16x8_t, ru);
}

// ---------------- attention: BM=128, LDS-shared B tiles, counted vmcnt -------
// grid 256 = 64 row-sets x 4 kq (kq = bx&3 -> one kq per XCD: B region L2-hot).
// Block = 128 rows x 2048 k; 8 waves = 4 rg x 2 ks2(1024k). B tile (16 KB,
// [kg][f][8j] linear) staged via global_load_lds, double-buffered, SHARED by
// the 4 rg-waves (per-CU TA bytes /4; device B traffic 1GB -> 256MB). One raw
// barrier/iter with vmcnt(4): staging drained, mask/s2 prefetch left in
// flight. Partials accP[kq]/lP[kq] merged by gat_merge.
__launch_bounds__(512, 2)
__global__ void gat_attn(const unsigned int* __restrict__ maskp,
                         const float* __restrict__ s1g, const float* __restrict__ s2g,
                         const unsigned short* __restrict__ whT2,
                         float* __restrict__ accP, float* __restrict__ lP) {
  __shared__ __align__(16) char stage[65536];  // 2 ks2 x 2 dbuf x 16 KB
  __shared__ float lred[2][128];
  float* redf = (float*)stage;  // reused post-loop: [64][256] f32

  const int tid = threadIdx.x;
  const int lane = tid & 63;
  const int w = tid >> 6;
  const int rg = w & 3;
  const int ks2 = w >> 2;
  const int rs = blockIdx.x >> 2;
  const int kq = blockIdx.x & 3;
  const int kbase = kq * 2048 + ks2 * 1024;
  const int r16 = lane & 15;
  const int kg = lane >> 4;
  const int row0 = rs * 128 + rg * 32 + r16;

  const unsigned int* mrow0 = maskp + (size_t)row0 * (NN / 32) + (kbase >> 5);
  const unsigned int* mrow1 = mrow0 + (size_t)16 * (NN / 32);
  const float* s2p = s2g + kbase + kg * 8;
  const char* wsrc = (const char*)whT2;
  const int ktq = kq * 64 + ks2 * 32;  // first ktile of this wave's slice
  const int qoB = rg * 4096;           // this wave's staging quarter (bytes)
  char* sbase = stage + ks2 * 32768;

  const float s1r0 = s1g[row0];
  const float s1r1 = s1g[row0 + 16];

  f32x4_t acc[2][16];
  const f32x4_t zero4 = {0.f, 0.f, 0.f, 0.f};
#pragma unroll
  for (int rt = 0; rt < 2; ++rt)
#pragma unroll
    for (int ct = 0; ct < 16; ++ct) acc[rt][ct] = zero4;

  float l0 = 0.f, l1 = 0.f;

  // ---- prologue: stage tile 0 -> buf0; load iter-0 mask/s2 ----
#pragma unroll
  for (int q = 0; q < 4; ++q)
    gload_lds16(wsrc + (size_t)ktq * 16384 + qoB + q * 1024 + lane * 16,
                sbase + qoB + q * 1024);
  __builtin_amdgcn_sched_barrier(0);
  unsigned int cw0 = mrow0[0];
  unsigned int cw1 = mrow1[0];
  float4 csl = *(const float4*)(s2p);
  float4 csh = *(const float4*)(s2p + 4);
  __builtin_amdgcn_sched_barrier(0);
  asm volatile("s_waitcnt vmcnt(4)" ::: "memory");
  __builtin_amdgcn_s_barrier();
  __builtin_amdgcn_sched_barrier(0);

  for (int it = 0; it < 32; ++it) {
    const int cur = it & 1;
    const int nxt = cur ^ 1;

    // ---- phase S: stage NEXT tile (4 x gload_lds, 1 KB each) ----
    if (it + 1 < 32) {
#pragma unroll
      for (int q = 0; q < 4; ++q)
        gload_lds16(wsrc + (size_t)(ktq + it + 1) * 16384 + qoB + q * 1024 + lane * 16,
                    sbase + nxt * 16384 + qoB + q * 1024);
    }
    __builtin_amdgcn_sched_barrier(0);

    // ---- phase P: next iter's mask/s2 -> regs (left in flight at barrier) --
    const int itn = (it + 1 < 32) ? it + 1 : it;
    unsigned int nw0 = mrow0[itn];
    unsigned int nw1 = mrow1[itn];
    float4 nsl = *(const float4*)(s2p + itn * 32);
    float4 nsh = *(const float4*)(s2p + itn * 32 + 4);
    __builtin_amdgcn_sched_barrier(0);

    // ---- phase R: ds_read CURRENT 16 B-frags (bank-even layout) ----
    const char* rb = sbase + cur * 16384 + kg * 4096 + r16 * 16;
    bf16x8_t b0 = *(const bf16x8_t*)(rb + 0 * 256);
    bf16x8_t b1 = *(const bf16x8_t*)(rb + 1 * 256);
    bf16x8_t b2 = *(const bf16x8_t*)(rb + 2 * 256);
    bf16x8_t b3 = *(const bf16x8_t*)(rb + 3 * 256);
    bf16x8_t b4 = *(const bf16x8_t*)(rb + 4 * 256);
    bf16x8_t b5 = *(const bf16x8_t*)(rb + 5 * 256);
    bf16x8_t b6 = *(const bf16x8_t*)(rb + 6 * 256);
    bf16x8_t b7 = *(const bf16x8_t*)(rb + 7 * 256);
    bf16x8_t b8 = *(const bf16x8_t*)(rb + 8 * 256);
    bf16x8_t b9 = *(const bf16x8_t*)(rb + 9 * 256);
    bf16x8_t b10 = *(const bf16x8_t*)(rb + 10 * 256);
    bf16x8_t b11 = *(const bf16x8_t*)(rb + 11 * 256);
    bf16x8_t b12 = *(const bf16x8_t*)(rb + 12 * 256);
    bf16x8_t b13 = *(const bf16x8_t*)(rb + 13 * 256);
    bf16x8_t b14 = *(const bf16x8_t*)(rb + 14 * 256);
    bf16x8_t b15 = *(const bf16x8_t*)(rb + 15 * 256);
    __builtin_amdgcn_sched_barrier(0);

    // ---- phase V: P fragments from current regs ----
    bf16x8_t af0 = make_afrag(s1r0, csl, csh, (cw0 >> (kg * 8)) & 0xffu, l0);
    bf16x8_t af1 = make_afrag(s1r1, csl, csh, (cw1 >> (kg * 8)) & 0xffu, l1);
    __builtin_amdgcn_sched_barrier(0);

    // ---- phase M: 64 MFMAs ----
    acc[0][0] = __builtin_amdgcn_mfma_f32_16x16x32_bf16(af0, b0, acc[0][0], 0, 0, 0);
    acc[1][0] = __builtin_amdgcn_mfma_f32_16x16x32_bf16(af1, b0, acc[1][0], 0, 0, 0);
    acc[0][1] = __builtin_amdgcn_mfma_f32_16x16x32_bf16(af0, b1, acc[0][1], 0, 0, 0);
    acc[1][1] = __builtin_amdgcn_mfma_f32_16x16x32_bf16(af1, b1, acc[1][1], 0, 0, 0);
    acc[0][2] = __builtin_amdgcn_mfma_f32_16x16x32_bf16(af0, b2, acc[0][2], 0, 0, 0);
    acc[1][2] = __builtin_amdgcn_mfma_f32_16x16x32_bf16(af1, b2, acc[1][2], 0, 0, 0);
    acc[0][3] = __builtin_amdgcn_mfma_f32_16x16x32_bf16(af0, b3, acc[0][3], 0, 0, 0);
    acc[1][3] = __builtin_amdgcn_mfma_f32_16x16x32_bf16(af1, b3, acc[1][3], 0, 0, 0);
    acc[0][4] = __builtin_amdgcn_mfma_f32_16x16x32_bf16(af0, b4, acc[0][4], 0, 0, 0);
    acc[1][4] = __builtin_amdgcn_mfma_f32_16x16x32_bf16(af1, b4, acc[1][4], 0, 0, 0);
    acc[0][5] = __builtin_amdgcn_mfma_f32_16x16x32_bf16(af0, b5, acc[0][5], 0, 0, 0);
    acc[1][5] = __builtin_amdgcn_mfma_f32_16x16x32_bf16(af1, b5, acc[1][5], 0, 0, 0);
    acc[0][6] = __builtin_amdgcn_mfma_f32_16x16x32_bf16(af0, b6, acc[0][6], 0, 0, 0);
    acc[1][6] = __builtin_amdgcn_mfma_f32_16x16x32_bf16(af1, b6, acc[1][6], 0, 0, 0);
    acc[0][7] = __builtin_amdgcn_mfma_f32_16x16x32_bf16(af0, b7, acc[0][7], 0, 0, 0);
    acc[1][7] = __builtin_amdgcn_mfma_f32_16x16x32_bf16(af1, b7, acc[1][7], 0, 0, 0);
    acc[0][8] = __builtin_amdgcn_mfma_f32_16x16x32_bf16(af0, b8, acc[0][8], 0, 0, 0);
    acc[1][8] = __builtin_amdgcn_mfma_f32_16x16x32_bf16(af1, b8, acc[1][8], 0, 0, 0);
    acc[0][9] = __builtin_amdgcn_mfma_f32_16x16x32_bf16(af0, b9, acc[0][9], 0, 0, 0);
    acc[1][9] = __builtin_amdgcn_mfma_f32_16x16x32_bf16(af1, b9, acc[1][9], 0, 0, 0);
    acc[0][10] = __builtin_amdgcn_mfma_f32_16x16x32_bf16(af0, b10, acc[0][10], 0, 0, 0);
    acc[1][10] = __builtin_amdgcn_mfma_f32_16x16x32_bf16(af1, b10, acc[1][10], 0, 0, 0);
    acc[0][11] = __builtin_amdgcn_mfma_f32_16x16x32_bf16(af0, b11, acc[0][11], 0, 0, 0);
    acc[1][11] = __builtin_amdgcn_mfma_f32_16x16x32_bf16(af1, b11, acc[1][11], 0, 0, 0);
    acc[0][12] = __builtin_amdgcn_mfma_f32_16x16x32_bf16(af0, b12, acc[0][12], 0, 0, 0);
    acc[1][12] = __builtin_amdgcn_mfma_f32_16x16x32_bf16(af1, b12, acc[1][12], 0, 0, 0);
    acc[0][13] = __builtin_amdgcn_mfma_f32_16x16x32_bf16(af0, b13, acc[0][13], 0, 0, 0);
    acc[1][13] = __builtin_amdgcn_mfma_f32_16x16x32_bf16(af1, b13, acc[1][13], 0, 0, 0);
    acc[0][14] = __builtin_amdgcn_mfma_f32_16x16x32_bf16(af0, b14, acc[0][14], 0, 0, 0);
    acc[1][14] = __builtin_amdgcn_mfma_f32_16x16x32_bf16(af1, b14, acc[1][14], 0, 0, 0);
    acc[0][15] = __builtin_amdgcn_mfma_f32_16x16x32_bf16(af0, b15, acc[0][15], 0, 0, 0);
    acc[1][15] = __builtin_amdgcn_mfma_f32_16x16x32_bf16(af1, b15, acc[1][15], 0, 0, 0);

    // ---- barrier: staging drained (vmcnt(4)); mask/s2 stay in flight ----
    if (it + 1 < 32) {
      asm volatile("s_waitcnt vmcnt(4)" ::: "memory");
      __builtin_amdgcn_s_barrier();
      __builtin_amdgcn_sched_barrier(0);
    }

    cw0 = nw0; cw1 = nw1; csl = nsl; csh = nsh;
  }

  __syncthreads();

  // ---- l partials ----
  l0 += __shfl_xor(l0, 16, 64);
  l0 += __shfl_xor(l0, 32, 64);
  l1 += __shfl_xor(l1, 16, 64);
  l1 += __shfl_xor(l1, 32, 64);
  if (lane < 16) {
    lred[ks2][rg * 32 + r16] = l0;
    lred[ks2][rg * 32 + 16 + r16] = l1;
  }
  __syncthreads();
  if (tid < 128) {
    lP[(size_t)kq * NN + rs * 128 + tid] = lred[0][tid] + lred[1][tid];
  }

  // ---- acc: merge ks2 pairs via LDS (2 phases of 64 rows), write accP ----
  float* ap = accP + (size_t)kq * NN * FD + (size_t)(rs * 128) * FD;
#pragma unroll
  for (int p = 0; p < 2; ++p) {
    if (p) __syncthreads();
    if (ks2 == 1 && (rg >> 1) == p) {
#pragma unroll
      for (int rt = 0; rt < 2; ++rt)
#pragma unroll
        for (int ct = 0; ct < 16; ++ct) {
          const int col = ct * 16 + r16;
#pragma unroll
          for (int g = 0; g < 4; ++g)
            redf[((rg & 1) * 32 + rt * 16 + kg * 4 + g) * 256 + col] = acc[rt][ct][g];
        }
    }
    __syncthreads();
    if (ks2 == 0 && (rg >> 1) == p) {
#pragma unroll
      for (int rt = 0; rt < 2; ++rt)
#pragma unroll
        for (int ct = 0; ct < 16; ++ct) {
          const int col = ct * 16 + r16;
#pragma unroll
          for (int g = 0; g < 4; ++g) {
            const int rl = rt * 16 + kg * 4 + g;
            ap[(size_t)(rg * 32 + rl) * FD + col] =
                acc[rt][ct][g] + redf[((rg & 1) * 32 + rl) * 256 + col];
          }
        }
    }
  }
}

// ---------------- merge: out[i][f] = sum_kq accP / sum_kq lP -----------------
__global__ void gat_merge(const float* __restrict__ accP, const float* __restrict__ lP,
                          float* __restrict__ out) {
  const int i = blockIdx.x;
  const int f = threadIdx.x;
  float s = 0.f, l = 0.f;
#pragma unroll
  for (int q = 0; q < 4; ++q) {
    s += accP[((size_t)q * NN + i) * FD + f];
    l += lP[(size_t)q * NN + i];
  }
  out[(size_t)i * FD + f] = s / l;
}

extern "C" void kernel_launch(void* const* d_in, const int* in_sizes, int n_in,
                              void* d_out, int out_size, void* d_ws, size_t ws_size,
                              hipStream_t stream) {
  const float* h = (const float*)d_in[0];
  const int* adj = (const int*)d_in[1];
  const float* W = (const float*)d_in[2];
  const float* a = (const float*)d_in[3];
  float* out = (float*)d_out;

  char* ws = (char*)d_ws;
  unsigned short* whT2 = (unsigned short*)ws;                        // 4 MB
  float* s1 = (float*)(ws + 4194304);                                // 32 KB
  float* s2 = (float*)(ws + 4194304 + 32768);                        // 32 KB
  float* c1 = (float*)(ws + 4194304 + 65536);                        // 1 KB
  float* c2 = (float*)(ws + 4194304 + 65536 + 1024);                 // 1 KB
  unsigned long long* mask64 = (unsigned long long*)(ws + 5242880);  // 8 MB
  float* accP = (float*)(ws + 16777216);                             // 32 MB
  float* lP = (float*)(ws + 50331648);                               // 128 KB

  gat_cvec<<<1, 256, 0, stream>>>(W, a, c1, c2);
  gat_prep<<<4608, 256, 0, stream>>>(h, W, adj, c1, c2, whT2, mask64, s1, s2);
  gat_attn<<<256, 512, 0, stream>>>((const unsigned int*)mask64, s1, s2, whT2, accP, lP);
  gat_merge<<<NN, FD, 0, stream>>>(accP, lP, out);
}